// Round 1
// baseline (1990.162 us; speedup 1.0000x reference)
//
#include <hip/hip_runtime.h>
#include <hip/hip_bf16.h>

#define M_ 4096
#define N_ 32000
#define K_ 4096
#define S_ 2048
#define SM1 2047
#define NROWS 4094

typedef __bf16 bf16x8 __attribute__((ext_vector_type(8)));
typedef float f32x4 __attribute__((ext_vector_type(4)));

#define GLDS16(g, l)                                                         \
  __builtin_amdgcn_global_load_lds(                                          \
      (__attribute__((address_space(1))) const void*)(g),                    \
      (__attribute__((address_space(3))) void*)(l), 16, 0, 0)

// ---------------------------------------------------------------- cvt kernel
__global__ __launch_bounds__(256) void cvt_f32_to_bf16(
    const float* __restrict__ in, bf16x8* __restrict__ out, long n8) {
  long i0 = (long)blockIdx.x * blockDim.x + threadIdx.x;
  long stride = (long)gridDim.x * blockDim.x;
  for (long i = i0; i < n8; i += stride) {
    const float4* p = reinterpret_cast<const float4*>(in) + i * 2;
    float4 a = p[0];
    float4 b = p[1];
    bf16x8 v;
    v[0] = (__bf16)a.x; v[1] = (__bf16)a.y; v[2] = (__bf16)a.z; v[3] = (__bf16)a.w;
    v[4] = (__bf16)b.x; v[5] = (__bf16)b.y; v[6] = (__bf16)b.z; v[7] = (__bf16)b.w;
    out[i] = v;
  }
}

// ---------------------------------------------------------------- GEMM
// C[m,n] = sum_k A[m,k] * B[n,k]   (A: hidden [M,K], B: W [N,K], both K-major)
// 128x128 tile, BK=32, 256 threads = 4 waves (2x2), each wave 64x64 (4x4 frags
// of 16x16x32 bf16 MFMA). Double-buffered LDS, global_load_lds width 16.
//
// LDS tile layout (per matrix, 8192 B): logical (row 0..127, chunk c 0..3 of
// 16B). Physical: rp = row>>1 (128 B rows), slot p = ((row&1)*4 + c) ^ (rp&7).
// Same XOR applied on the staging *source* address (linear LDS dest) and on
// the ds_read address -> bank-uniform, 2-way max aliasing (free).
template <bool PRECONV>
__global__ __launch_bounds__(256) void gemm_kernel(
    const void* __restrict__ Ap, const void* __restrict__ Bp,
    float* __restrict__ Cp) {
  __shared__ __align__(1024) unsigned char smem[2][16384];  // [buf][A:0..8191 | B:8192..]

  const int tid = threadIdx.x;
  const int bid = blockIdx.x;
  // XCD-aware swizzle: 8000 blocks, 8 XCDs, 1000 per chunk (8000 % 8 == 0).
  const int swz = (bid & 7) * 1000 + (bid >> 3);
  const int nblk = swz >> 5;   // 0..249  (n-panel major: 32 consecutive share W panel)
  const int mblk = swz & 31;   // 0..31
  const int m0 = mblk * 128;
  const int n0 = nblk * 128;

  const int w = tid >> 6;
  const int lane = tid & 63;
  const int wm = w >> 1;
  const int wn = w & 1;
  const int rl = lane & 15;   // fragment row/col within 16
  const int cl = lane >> 4;   // k-chunk 0..3

  f32x4 acc[4][4];
#pragma unroll
  for (int i = 0; i < 4; ++i)
#pragma unroll
    for (int j = 0; j < 4; ++j) acc[i][j] = (f32x4){0.f, 0.f, 0.f, 0.f};

  auto stage = [&](int buf, int kt) {
    const int k0 = kt * 32;
    if constexpr (PRECONV) {
      const __bf16* A = (const __bf16*)Ap;
      const __bf16* B = (const __bf16*)Bp;
#pragma unroll
      for (int j = 0; j < 2; ++j) {
        const int t = j * 256 + tid;       // chunk 0..511
        const int rp = t >> 3;
        const int ps = t & 7;
        const int pl = ps ^ (rp & 7);      // inverse-permuted source
        const int row = rp * 2 + (pl >> 2);
        const int c = pl & 3;
        GLDS16(A + (size_t)(m0 + row) * K_ + k0 + c * 8, &smem[buf][t * 16]);
        GLDS16(B + (size_t)(n0 + row) * K_ + k0 + c * 8, &smem[buf][8192 + t * 16]);
      }
    } else {
      const float* A = (const float*)Ap;
      const float* B = (const float*)Bp;
#pragma unroll
      for (int j = 0; j < 2; ++j) {
        const int t = j * 256 + tid;
        const int row = t >> 2;
        const int c = t & 3;
        const int rp = row >> 1;
        const int pp = ((row & 1) * 4 + c) ^ (rp & 7);
        const int lb = rp * 128 + pp * 16;
        {
          const float4* g = (const float4*)(A + (size_t)(m0 + row) * K_ + k0 + c * 8);
          float4 x = g[0], y = g[1];
          bf16x8 v;
          v[0] = (__bf16)x.x; v[1] = (__bf16)x.y; v[2] = (__bf16)x.z; v[3] = (__bf16)x.w;
          v[4] = (__bf16)y.x; v[5] = (__bf16)y.y; v[6] = (__bf16)y.z; v[7] = (__bf16)y.w;
          *(bf16x8*)(&smem[buf][lb]) = v;
        }
        {
          const float4* g = (const float4*)(B + (size_t)(n0 + row) * K_ + k0 + c * 8);
          float4 x = g[0], y = g[1];
          bf16x8 v;
          v[0] = (__bf16)x.x; v[1] = (__bf16)x.y; v[2] = (__bf16)x.z; v[3] = (__bf16)x.w;
          v[4] = (__bf16)y.x; v[5] = (__bf16)y.y; v[6] = (__bf16)y.z; v[7] = (__bf16)y.w;
          *(bf16x8*)(&smem[buf][8192 + lb]) = v;
        }
      }
    }
  };

  auto ldfrag = [&](const unsigned char* base, int row, int c) -> bf16x8 {
    const int rp = row >> 1;
    const int pp = ((row & 1) * 4 + c) ^ (rp & 7);
    return *(const bf16x8*)(base + rp * 128 + pp * 16);
  };

  auto compute = [&](int buf) {
    const unsigned char* bA = smem[buf];
    const unsigned char* bB = smem[buf] + 8192;
    bf16x8 af[4], bfv[4];
#pragma unroll
    for (int i = 0; i < 4; ++i) af[i] = ldfrag(bA, wm * 64 + i * 16 + rl, cl);
#pragma unroll
    for (int j = 0; j < 4; ++j) bfv[j] = ldfrag(bB, wn * 64 + j * 16 + rl, cl);
#pragma unroll
    for (int i = 0; i < 4; ++i)
#pragma unroll
      for (int j = 0; j < 4; ++j)
        acc[i][j] = __builtin_amdgcn_mfma_f32_16x16x32_bf16(af[i], bfv[j],
                                                            acc[i][j], 0, 0, 0);
  };

  stage(0, 0);
  __syncthreads();
  const int NT = K_ / 32;  // 128
  for (int kt = 0; kt < NT; kt += 2) {
    if (kt + 1 < NT) stage(1, kt + 1);
    compute(0);
    __syncthreads();
    if (kt + 2 < NT) stage(0, kt + 2);
    compute(1);
    __syncthreads();
  }

  // Epilogue: C/D layout col = lane&15, row = (lane>>4)*4 + reg  [m89-verified]
#pragma unroll
  for (int i = 0; i < 4; ++i)
#pragma unroll
    for (int j = 0; j < 4; ++j)
#pragma unroll
      for (int r = 0; r < 4; ++r) {
        const int grow = m0 + wm * 64 + i * 16 + cl * 4 + r;
        const int gcol = n0 + wn * 64 + j * 16 + rl;
        Cp[(size_t)grow * N_ + gcol] = acc[i][j][r];
      }
}

// ---------------------------------------------------------------- CE loss
__device__ __forceinline__ float wred_max(float v) {
#pragma unroll
  for (int o = 32; o > 0; o >>= 1) v = fmaxf(v, __shfl_xor(v, o));
  return v;
}
__device__ __forceinline__ float wred_sum(float v) {
#pragma unroll
  for (int o = 32; o > 0; o >>= 1) v += __shfl_xor(v, o);
  return v;
}

__global__ __launch_bounds__(256) void ce_rows(const float* __restrict__ logits,
                                               const int* __restrict__ labels,
                                               float* __restrict__ nll) {
  const int r = blockIdx.x;  // 0..4093
  const int b = r / SM1;
  const int t = r - b * SM1;
  const float* row = logits + (size_t)(b * S_ + t) * N_;
  const int lane = threadIdx.x & 63;
  const int w = threadIdx.x >> 6;
  __shared__ float red[8];

  float m = -3.4e38f;
  for (int v = threadIdx.x; v < N_; v += 256) m = fmaxf(m, row[v]);
  float wm_ = wred_max(m);
  if (lane == 0) red[w] = wm_;
  __syncthreads();
  m = fmaxf(fmaxf(red[0], red[1]), fmaxf(red[2], red[3]));

  float s = 0.f;
  for (int v = threadIdx.x; v < N_; v += 256) s += __expf(row[v] - m);
  float ws = wred_sum(s);
  if (lane == 0) red[4 + w] = ws;
  __syncthreads();
  if (threadIdx.x == 0) {
    const float tot = red[4] + red[5] + red[6] + red[7];
    const int lbl = labels[b * S_ + t + 1];
    nll[r] = m + __logf(tot) - row[lbl];
  }
}

__global__ __launch_bounds__(256) void reduce_loss(const float* __restrict__ nll,
                                                   float* __restrict__ out) {
  float s = 0.f;
  for (int i = threadIdx.x; i < NROWS; i += 256) s += nll[i];
  s = wred_sum(s);
  __shared__ float sb[4];
  if ((threadIdx.x & 63) == 0) sb[threadIdx.x >> 6] = s;
  __syncthreads();
  if (threadIdx.x == 0) out[0] = (sb[0] + sb[1] + sb[2] + sb[3]) / (float)NROWS;
}

// ---------------------------------------------------------------- launch
extern "C" void kernel_launch(void* const* d_in, const int* in_sizes, int n_in,
                              void* d_out, int out_size, void* d_ws,
                              size_t ws_size, hipStream_t stream) {
  const float* h = (const float*)d_in[0];
  const float* Wf = (const float*)d_in[1];
  const int* labels = (const int*)d_in[2];
  float* out = (float*)d_out;
  float* logits = out + 1;

  const size_t abytes = (size_t)M_ * K_ * 2;  // 33,554,432
  const size_t bbytes = (size_t)N_ * K_ * 2;  // 262,144,000
  const size_t need = abytes + bbytes + (size_t)NROWS * sizeof(float);

  if (ws_size >= need) {
    unsigned char* base = (unsigned char*)d_ws;
    void* hA = (void*)base;
    void* wB = (void*)(base + abytes);
    float* nll = (float*)(base + abytes + bbytes);
    cvt_f32_to_bf16<<<2048, 256, 0, stream>>>(h, (bf16x8*)hA,
                                              (long)((size_t)M_ * K_ / 8));
    cvt_f32_to_bf16<<<4096, 256, 0, stream>>>(Wf, (bf16x8*)wB,
                                              (long)((size_t)N_ * K_ / 8));
    gemm_kernel<true><<<8000, 256, 0, stream>>>(hA, wB, logits);
    ce_rows<<<4094, 256, 0, stream>>>(logits, labels, nll);
    reduce_loss<<<1, 256, 0, stream>>>(nll, out);
  } else {
    // Fallback: fused convert-in-staging GEMM (reg-stage + ds_write), tiny ws.
    float* nll = (float*)d_ws;
    gemm_kernel<false><<<8000, 256, 0, stream>>>((const void*)h, (const void*)Wf,
                                                 logits);
    ce_rows<<<4094, 256, 0, stream>>>(logits, labels, nll);
    reduce_loss<<<1, 256, 0, stream>>>(nll, out);
  }
}

// Round 2
// 1382.449 us; speedup vs baseline: 1.4396x; 1.4396x over previous
//
#include <hip/hip_runtime.h>
#include <hip/hip_bf16.h>

#define M_ 4096
#define N_ 32000
#define K_ 4096
#define S_ 2048
#define SM1 2047
#define NROWS 4094
#define NT_ 64  // K-tiles of BK=64

typedef __bf16 bf16x8 __attribute__((ext_vector_type(8)));
typedef float f32x4 __attribute__((ext_vector_type(4)));

#define GLDS16(g, l)                                                         \
  __builtin_amdgcn_global_load_lds(                                          \
      (__attribute__((address_space(1))) const void*)(g),                    \
      (__attribute__((address_space(3))) void*)(l), 16, 0, 0)
#define BAR() __builtin_amdgcn_s_barrier()
#define PRIO1() __builtin_amdgcn_s_setprio(1)
#define PRIO0() __builtin_amdgcn_s_setprio(0)
#define VMCNT(n) asm volatile("s_waitcnt vmcnt(" #n ")" ::: "memory")
#define LGKM0() asm volatile("s_waitcnt lgkmcnt(0)" ::: "memory")

// ---------------------------------------------------------------- cvt kernel
__global__ __launch_bounds__(256) void cvt_f32_to_bf16(
    const float* __restrict__ in, bf16x8* __restrict__ out, long n8) {
  long i0 = (long)blockIdx.x * blockDim.x + threadIdx.x;
  long stride = (long)gridDim.x * blockDim.x;
  for (long i = i0; i < n8; i += stride) {
    const float4* p = reinterpret_cast<const float4*>(in) + i * 2;
    float4 a = p[0];
    float4 b = p[1];
    bf16x8 v;
    v[0] = (__bf16)a.x; v[1] = (__bf16)a.y; v[2] = (__bf16)a.z; v[3] = (__bf16)a.w;
    v[4] = (__bf16)b.x; v[5] = (__bf16)b.y; v[6] = (__bf16)b.z; v[7] = (__bf16)b.w;
    out[i] = v;
  }
}

// ---------------------------------------------------------------- GEMM 256x256 8-phase
// C[m,n] = sum_k A[m,k]*B[n,k]. BM=BN=256, BK=64, 512 threads = 8 waves (2m x 4n),
// per-wave 128x64 output = acc[8][4] of 16x16 frags. LDS 128 KiB: 2 dbuf x
// (A 32KB | B 32KB). Per K-tile: 4 phases = C-quadrants (qm,qn) of 16 MFMA each;
// 2 global_load_lds staged per phase for tile s+1; counted vmcnt at phase-2 end
// (vmcnt 4) and tile boundary (vmcnt 2) -- loads never drained while recent.
//
// LDS layout per matrix tile (256 rows x 64 cols bf16): byte = row*128 +
// slot*16, slot = c ^ (row&7), c = 16B col-chunk (0..7). Staged with linear
// dest + inverse-permuted global source (rule #21); ds_read applies the XOR.
__global__ __launch_bounds__(512, 2) void gemm256(
    const __bf16* __restrict__ A, const __bf16* __restrict__ B,
    float* __restrict__ C) {
  __shared__ __align__(1024) unsigned char smem[2][65536];

  const int tid = threadIdx.x;
  const int bid = blockIdx.x;
  // Bijective XCD swizzle (2000 blocks % 8 == 0), n-panel-major within XCD:
  // each XCD works a disjoint band of n-panels; B panel stays L2-hot.
  const int wg = (bid & 7) * 250 + (bid >> 3);
  const int nblk = wg >> 4;  // 0..124
  const int mblk = wg & 15;  // 0..15
  const int m0 = mblk * 256;
  const int n0 = nblk * 256;

  const int w = tid >> 6;
  const int lane = tid & 63;
  const int wm = w >> 2;  // 0..1
  const int wn = w & 3;   // 0..3
  const int rl = lane & 15;
  const int cl = lane >> 4;
  const int srow = tid >> 3;              // staging: row-local 0..63
  const int sc = (tid & 7) ^ (srow & 7);  // staging: pre-swizzled source chunk
  const int sdst = tid * 16;

  f32x4 acc[8][4];
#pragma unroll
  for (int i = 0; i < 8; ++i)
#pragma unroll
    for (int j = 0; j < 4; ++j) acc[i][j] = (f32x4){0.f, 0.f, 0.f, 0.f};

  auto stA = [&](int nbuf, int kt, int r0) {
    GLDS16(A + (size_t)(m0 + r0 + srow) * K_ + kt * 64 + sc * 8,
           &smem[nbuf][r0 * 128 + sdst]);
  };
  auto stB = [&](int nbuf, int kt, int r0) {
    GLDS16(B + (size_t)(n0 + r0 + srow) * K_ + kt * 64 + sc * 8,
           &smem[nbuf][32768 + r0 * 128 + sdst]);
  };
  auto ld = [&](const unsigned char* base, int row, int c) -> bf16x8 {
    return *(const bf16x8*)(base + row * 128 + ((c ^ (row & 7)) << 4));
  };

  // Prologue: tile 0, issue order == consumption order (A0,A2,B*, then A1,A3).
  stA(0, 0, 0); stA(0, 0, 128);
  stB(0, 0, 0); stB(0, 0, 64); stB(0, 0, 128); stB(0, 0, 192);
  stA(0, 0, 64); stA(0, 0, 192);
  VMCNT(2);
  BAR();

  bf16x8 a[4][2], b0[2][2], b1[2][2];
  for (int s = 0; s < NT_; ++s) {
    const int cur = s & 1;
    const int nxt = cur ^ 1;
    const unsigned char* bA = smem[cur];
    const unsigned char* bB = smem[cur] + 32768;
    const bool st = (s + 1 < NT_);
    const int k1 = s + 1;

    // -------- phase 1: quadrant (0,0)
#pragma unroll
    for (int ii = 0; ii < 4; ++ii)
#pragma unroll
      for (int ks = 0; ks < 2; ++ks)
        a[ii][ks] = ld(bA, wm * 128 + ii * 16 + rl, ks * 4 + cl);
#pragma unroll
    for (int jj = 0; jj < 2; ++jj)
#pragma unroll
      for (int ks = 0; ks < 2; ++ks)
        b0[jj][ks] = ld(bB, wn * 64 + jj * 16 + rl, ks * 4 + cl);
    if (st) { stA(nxt, k1, 0); stA(nxt, k1, 128); }
    BAR();
    LGKM0();
    PRIO1();
#pragma unroll
    for (int ii = 0; ii < 4; ++ii)
#pragma unroll
      for (int jj = 0; jj < 2; ++jj)
#pragma unroll
        for (int ks = 0; ks < 2; ++ks)
          acc[ii][jj] = __builtin_amdgcn_mfma_f32_16x16x32_bf16(
              a[ii][ks], b0[jj][ks], acc[ii][jj], 0, 0, 0);
    PRIO0();
    BAR();

    // -------- phase 2: quadrant (0,1)
#pragma unroll
    for (int jj = 0; jj < 2; ++jj)
#pragma unroll
      for (int ks = 0; ks < 2; ++ks)
        b1[jj][ks] = ld(bB, wn * 64 + 32 + jj * 16 + rl, ks * 4 + cl);
    if (st) { stB(nxt, k1, 0); stB(nxt, k1, 64); }
    BAR();
    LGKM0();
    PRIO1();
#pragma unroll
    for (int ii = 0; ii < 4; ++ii)
#pragma unroll
      for (int jj = 0; jj < 2; ++jj)
#pragma unroll
        for (int ks = 0; ks < 2; ++ks)
          acc[ii][2 + jj] = __builtin_amdgcn_mfma_f32_16x16x32_bf16(
              a[ii][ks], b1[jj][ks], acc[ii][2 + jj], 0, 0, 0);
    PRIO0();
    if (st) { VMCNT(4); } else { VMCNT(0); }  // guard phase-3 A reads
    BAR();

    // -------- phase 3: quadrant (1,0)
#pragma unroll
    for (int ii = 0; ii < 4; ++ii)
#pragma unroll
      for (int ks = 0; ks < 2; ++ks)
        a[ii][ks] = ld(bA, wm * 128 + 64 + ii * 16 + rl, ks * 4 + cl);
    if (st) { stB(nxt, k1, 128); stB(nxt, k1, 192); }
    BAR();
    LGKM0();
    PRIO1();
#pragma unroll
    for (int ii = 0; ii < 4; ++ii)
#pragma unroll
      for (int jj = 0; jj < 2; ++jj)
#pragma unroll
        for (int ks = 0; ks < 2; ++ks)
          acc[4 + ii][jj] = __builtin_amdgcn_mfma_f32_16x16x32_bf16(
              a[ii][ks], b0[jj][ks], acc[4 + ii][jj], 0, 0, 0);
    PRIO0();
    BAR();

    // -------- phase 4: quadrant (1,1)
    if (st) { stA(nxt, k1, 64); stA(nxt, k1, 192); }
    BAR();
    PRIO1();
#pragma unroll
    for (int ii = 0; ii < 4; ++ii)
#pragma unroll
      for (int jj = 0; jj < 2; ++jj)
#pragma unroll
        for (int ks = 0; ks < 2; ++ks)
          acc[4 + ii][2 + jj] = __builtin_amdgcn_mfma_f32_16x16x32_bf16(
              a[ii][ks], b1[jj][ks], acc[4 + ii][2 + jj], 0, 0, 0);
    PRIO0();
    if (st) { VMCNT(2); }  // tile boundary: leave newest (A1,A3) in flight
    BAR();
  }

  // Epilogue: C/D layout col = lane&15, row = (lane>>4)*4 + reg  [m89]
#pragma unroll
  for (int i = 0; i < 8; ++i)
#pragma unroll
    for (int j = 0; j < 4; ++j)
#pragma unroll
      for (int r = 0; r < 4; ++r) {
        const int grow = m0 + wm * 128 + i * 16 + cl * 4 + r;
        const int gcol = n0 + wn * 64 + j * 16 + rl;
        C[(size_t)grow * N_ + gcol] = acc[i][j][r];
      }
}

// ---------------------------------------------------------------- fallback GEMM (fp32 in, 128^2)
__global__ __launch_bounds__(256) void gemm_fb(const float* __restrict__ Ap,
                                               const float* __restrict__ Bp,
                                               float* __restrict__ Cp) {
  __shared__ __align__(1024) unsigned char smem[2][16384];
  const int tid = threadIdx.x;
  const int bid = blockIdx.x;
  const int swz = (bid & 7) * 1000 + (bid >> 3);
  const int nblk = swz >> 5;
  const int mblk = swz & 31;
  const int m0 = mblk * 128;
  const int n0 = nblk * 128;
  const int w = tid >> 6, lane = tid & 63;
  const int wm = w >> 1, wn = w & 1;
  const int rl = lane & 15, cl = lane >> 4;

  f32x4 acc[4][4];
#pragma unroll
  for (int i = 0; i < 4; ++i)
#pragma unroll
    for (int j = 0; j < 4; ++j) acc[i][j] = (f32x4){0.f, 0.f, 0.f, 0.f};

  auto stage = [&](int buf, int kt) {
    const int k0 = kt * 32;
#pragma unroll
    for (int j = 0; j < 2; ++j) {
      const int t = j * 256 + tid;
      const int row = t >> 2;
      const int c = t & 3;
      const int rp = row >> 1;
      const int pp = ((row & 1) * 4 + c) ^ (rp & 7);
      const int lb = rp * 128 + pp * 16;
      {
        const float4* g = (const float4*)(Ap + (size_t)(m0 + row) * K_ + k0 + c * 8);
        float4 x = g[0], y = g[1];
        bf16x8 v;
        v[0] = (__bf16)x.x; v[1] = (__bf16)x.y; v[2] = (__bf16)x.z; v[3] = (__bf16)x.w;
        v[4] = (__bf16)y.x; v[5] = (__bf16)y.y; v[6] = (__bf16)y.z; v[7] = (__bf16)y.w;
        *(bf16x8*)(&smem[buf][lb]) = v;
      }
      {
        const float4* g = (const float4*)(Bp + (size_t)(n0 + row) * K_ + k0 + c * 8);
        float4 x = g[0], y = g[1];
        bf16x8 v;
        v[0] = (__bf16)x.x; v[1] = (__bf16)x.y; v[2] = (__bf16)x.z; v[3] = (__bf16)x.w;
        v[4] = (__bf16)y.x; v[5] = (__bf16)y.y; v[6] = (__bf16)y.z; v[7] = (__bf16)y.w;
        *(bf16x8*)(&smem[buf][8192 + lb]) = v;
      }
    }
  };
  auto ldfrag = [&](const unsigned char* base, int row, int c) -> bf16x8 {
    const int rp = row >> 1;
    const int pp = ((row & 1) * 4 + c) ^ (rp & 7);
    return *(const bf16x8*)(base + rp * 128 + pp * 16);
  };
  auto compute = [&](int buf) {
    const unsigned char* bA = smem[buf];
    const unsigned char* bB = smem[buf] + 8192;
    bf16x8 af[4], bfv[4];
#pragma unroll
    for (int i = 0; i < 4; ++i) af[i] = ldfrag(bA, wm * 64 + i * 16 + rl, cl);
#pragma unroll
    for (int j = 0; j < 4; ++j) bfv[j] = ldfrag(bB, wn * 64 + j * 16 + rl, cl);
#pragma unroll
    for (int i = 0; i < 4; ++i)
#pragma unroll
      for (int j = 0; j < 4; ++j)
        acc[i][j] = __builtin_amdgcn_mfma_f32_16x16x32_bf16(af[i], bfv[j],
                                                            acc[i][j], 0, 0, 0);
  };

  stage(0, 0);
  __syncthreads();
  for (int kt = 0; kt < 128; kt += 2) {
    if (kt + 1 < 128) stage(1, kt + 1);
    compute(0);
    __syncthreads();
    if (kt + 2 < 128) stage(0, kt + 2);
    compute(1);
    __syncthreads();
  }
#pragma unroll
  for (int i = 0; i < 4; ++i)
#pragma unroll
    for (int j = 0; j < 4; ++j)
#pragma unroll
      for (int r = 0; r < 4; ++r) {
        const int grow = m0 + wm * 64 + i * 16 + cl * 4 + r;
        const int gcol = n0 + wn * 64 + j * 16 + rl;
        Cp[(size_t)grow * N_ + gcol] = acc[i][j][r];
      }
}

// ---------------------------------------------------------------- CE loss
__device__ __forceinline__ float wred_max(float v) {
#pragma unroll
  for (int o = 32; o > 0; o >>= 1) v = fmaxf(v, __shfl_xor(v, o));
  return v;
}
__device__ __forceinline__ float wred_sum(float v) {
#pragma unroll
  for (int o = 32; o > 0; o >>= 1) v += __shfl_xor(v, o);
  return v;
}

__global__ __launch_bounds__(256) void ce_rows(const float* __restrict__ logits,
                                               const int* __restrict__ labels,
                                               float* __restrict__ nll) {
  const int r = blockIdx.x;
  const int b = r / SM1;
  const int t = r - b * SM1;
  const float* row = logits + (size_t)(b * S_ + t) * N_;
  const int lane = threadIdx.x & 63;
  const int w = threadIdx.x >> 6;
  __shared__ float red[8];

  float m = -3.4e38f;
  for (int v = threadIdx.x; v < N_; v += 256) m = fmaxf(m, row[v]);
  float wm_ = wred_max(m);
  if (lane == 0) red[w] = wm_;
  __syncthreads();
  m = fmaxf(fmaxf(red[0], red[1]), fmaxf(red[2], red[3]));

  float s = 0.f;
  for (int v = threadIdx.x; v < N_; v += 256) s += __expf(row[v] - m);
  float ws = wred_sum(s);
  if (lane == 0) red[4 + w] = ws;
  __syncthreads();
  if (threadIdx.x == 0) {
    const float tot = red[4] + red[5] + red[6] + red[7];
    const int lbl = labels[b * S_ + t + 1];
    nll[r] = m + __logf(tot) - row[lbl];
  }
}

__global__ __launch_bounds__(256) void reduce_loss(const float* __restrict__ nll,
                                                   float* __restrict__ out) {
  float s = 0.f;
  for (int i = threadIdx.x; i < NROWS; i += 256) s += nll[i];
  s = wred_sum(s);
  __shared__ float sb[4];
  if ((threadIdx.x & 63) == 0) sb[threadIdx.x >> 6] = s;
  __syncthreads();
  if (threadIdx.x == 0) out[0] = (sb[0] + sb[1] + sb[2] + sb[3]) / (float)NROWS;
}

// ---------------------------------------------------------------- launch
extern "C" void kernel_launch(void* const* d_in, const int* in_sizes, int n_in,
                              void* d_out, int out_size, void* d_ws,
                              size_t ws_size, hipStream_t stream) {
  const float* h = (const float*)d_in[0];
  const float* Wf = (const float*)d_in[1];
  const int* labels = (const int*)d_in[2];
  float* out = (float*)d_out;
  float* logits = out + 1;

  const size_t abytes = (size_t)M_ * K_ * 2;
  const size_t bbytes = (size_t)N_ * K_ * 2;
  const size_t need = abytes + bbytes + (size_t)NROWS * sizeof(float);

  if (ws_size >= need) {
    unsigned char* base = (unsigned char*)d_ws;
    __bf16* hA = (__bf16*)base;
    __bf16* wB = (__bf16*)(base + abytes);
    float* nll = (float*)(base + abytes + bbytes);
    cvt_f32_to_bf16<<<2048, 256, 0, stream>>>(h, (bf16x8*)hA,
                                              (long)((size_t)M_ * K_ / 8));
    cvt_f32_to_bf16<<<4096, 256, 0, stream>>>(Wf, (bf16x8*)wB,
                                              (long)((size_t)N_ * K_ / 8));
    gemm256<<<2000, 512, 0, stream>>>(hA, wB, logits);
    ce_rows<<<4094, 256, 0, stream>>>(logits, labels, nll);
    reduce_loss<<<1, 256, 0, stream>>>(nll, out);
  } else {
    float* nll = (float*)d_ws;
    gemm_fb<<<8000, 256, 0, stream>>>(h, Wf, logits);
    ce_rows<<<4094, 256, 0, stream>>>(logits, labels, nll);
    reduce_loss<<<1, 256, 0, stream>>>(nll, out);
  }
}

// Round 3
// 1351.194 us; speedup vs baseline: 1.4729x; 1.0231x over previous
//
#include <hip/hip_runtime.h>
#include <hip/hip_bf16.h>

#define M_ 4096
#define N_ 32000
#define K_ 4096
#define S_ 2048
#define SM1 2047
#define NROWS 4094
#define NT_ 128  // K-tiles of BK=32

typedef __bf16 bf16x8 __attribute__((ext_vector_type(8)));
typedef float f32x4 __attribute__((ext_vector_type(4)));

#define GLDS16(g, l)                                                         \
  __builtin_amdgcn_global_load_lds(                                          \
      (__attribute__((address_space(1))) const void*)(g),                    \
      (__attribute__((address_space(3))) void*)(l), 16, 0, 0)
#define BAR() __builtin_amdgcn_s_barrier()
#define PRIO1() __builtin_amdgcn_s_setprio(1)
#define PRIO0() __builtin_amdgcn_s_setprio(0)
#define VMCNT(n) asm volatile("s_waitcnt vmcnt(" #n ")" ::: "memory")
#define LGKM0() asm volatile("s_waitcnt lgkmcnt(0)" ::: "memory")

// ---------------------------------------------------------------- cvt kernel
__global__ __launch_bounds__(256) void cvt_f32_to_bf16(
    const float* __restrict__ in, bf16x8* __restrict__ out, long n8) {
  long i0 = (long)blockIdx.x * blockDim.x + threadIdx.x;
  long stride = (long)gridDim.x * blockDim.x;
  for (long i = i0; i < n8; i += stride) {
    const float4* p = reinterpret_cast<const float4*>(in) + i * 2;
    float4 a = p[0];
    float4 b = p[1];
    bf16x8 v;
    v[0] = (__bf16)a.x; v[1] = (__bf16)a.y; v[2] = (__bf16)a.z; v[3] = (__bf16)a.w;
    v[4] = (__bf16)b.x; v[5] = (__bf16)b.y; v[6] = (__bf16)b.z; v[7] = (__bf16)b.w;
    out[i] = v;
  }
}

// ---------------------------------------------------------------- GEMM 256x256, BK=32, 4-deep pipeline
// C[m,n] = sum_k A[m,k]*B[n,k]. BM=BN=256, BK=32, 512 threads = 8 waves
// (2m x 4n), per-wave 128x64 = acc[8][4] of 16x16 frags (16x16x32 MFMA).
// LDS: 4 buffers x 32 KB (A 16K | B 16K). Prefetch 3 tiles deep: loads for
// tile s are issued during tile s-3 (A in phase 1, B in phase 2), so every
// load has >=2 full tile-times (~800+ cy) before its landing is required.
// One loose wait per tile: vmcnt(8) at the boundary leaves tiles s+2,s+3
// (8 loads) in flight. Tail: vmcnt(4) entering tile NT-2, vmcnt(0) entering
// NT-1.  WAR-safe: tile-s staging writes buf[(s+3)&3] == buf[(s-1)&3], whose
// readers all passed the boundary barrier at end of tile s-1.
//
// LDS layout per matrix (256 rows x 64 B): byte = row*64 + slot*16,
// slot = c ^ (row&3). Linear GLDS dest + inverse-permuted global source
// (rule #21); ds_read applies the same XOR -> <=2-way bank aliasing (free).
__global__ __launch_bounds__(512, 2) void gemm256(
    const __bf16* __restrict__ A, const __bf16* __restrict__ B,
    float* __restrict__ C) {
  __shared__ __align__(1024) unsigned char smem[4][32768];

  const int tid = threadIdx.x;
  const int bid = blockIdx.x;
  // Bijective XCD swizzle (2000 % 8 == 0), n-panel-major within XCD.
  const int wg = (bid & 7) * 250 + (bid >> 3);
  const int nblk = wg >> 4;  // 0..124
  const int mblk = wg & 15;  // 0..15
  const int m0 = mblk * 256;
  const int n0 = nblk * 256;

  const int w = tid >> 6;
  const int lane = tid & 63;
  const int wm = w >> 2;  // 0..1
  const int wn = w & 3;   // 0..3
  const int rl = lane & 15;
  const int cl = lane >> 4;  // k-chunk 0..3

  f32x4 acc[8][4];
#pragma unroll
  for (int i = 0; i < 8; ++i)
#pragma unroll
    for (int j = 0; j < 4; ++j) acc[i][j] = (f32x4){0.f, 0.f, 0.f, 0.f};

  auto stA = [&](unsigned char* buf, int kt) {
#pragma unroll
    for (int j = 0; j < 2; ++j) {
      const int cd = j * 512 + tid;          // dest 16B chunk, linear
      const int row = cd >> 2;
      const int c = (cd & 3) ^ (row & 3);    // inverse-permuted source chunk
      GLDS16(A + (size_t)(m0 + row) * K_ + kt * 32 + c * 8, buf + cd * 16);
    }
  };
  auto stB = [&](unsigned char* buf, int kt) {
#pragma unroll
    for (int j = 0; j < 2; ++j) {
      const int cd = j * 512 + tid;
      const int row = cd >> 2;
      const int c = (cd & 3) ^ (row & 3);
      GLDS16(B + (size_t)(n0 + row) * K_ + kt * 32 + c * 8,
             buf + 16384 + cd * 16);
    }
  };
  auto ld = [&](const unsigned char* base, int row) -> bf16x8 {
    return *(const bf16x8*)(base + row * 64 + (((cl ^ row) & 3) << 4));
  };

  // Prologue: stage tiles 0,1,2 (12 loads); wait tile 0 (leave 8 in flight).
  stA(smem[0], 0); stB(smem[0], 0);
  stA(smem[1], 1); stB(smem[1], 1);
  stA(smem[2], 2); stB(smem[2], 2);
  VMCNT(8);
  BAR();

  bf16x8 a[4], b[4];
  for (int s = 0; s < NT_; ++s) {
    const unsigned char* bufc = smem[s & 3];
    unsigned char* bufn = smem[(s + 3) & 3];
    const bool st = (s < NT_ - 3);

    // -------- phase 1: ii 0..3
#pragma unroll
    for (int i = 0; i < 4; ++i) a[i] = ld(bufc, wm * 128 + i * 16 + rl);
#pragma unroll
    for (int j = 0; j < 4; ++j) b[j] = ld(bufc + 16384, wn * 64 + j * 16 + rl);
    if (st) stA(bufn, s + 3);
    BAR();
    LGKM0();
    PRIO1();
#pragma unroll
    for (int ii = 0; ii < 4; ++ii)
#pragma unroll
      for (int jj = 0; jj < 4; ++jj)
        acc[ii][jj] = __builtin_amdgcn_mfma_f32_16x16x32_bf16(
            a[ii], b[jj], acc[ii][jj], 0, 0, 0);
    PRIO0();
    BAR();

    // -------- phase 2: ii 4..7 (b held in registers)
#pragma unroll
    for (int i = 0; i < 4; ++i) a[i] = ld(bufc, wm * 128 + 64 + i * 16 + rl);
    if (st) stB(bufn, s + 3);
    BAR();
    LGKM0();
    PRIO1();
#pragma unroll
    for (int ii = 0; ii < 4; ++ii)
#pragma unroll
      for (int jj = 0; jj < 4; ++jj)
        acc[4 + ii][jj] = __builtin_amdgcn_mfma_f32_16x16x32_bf16(
            a[ii], b[jj], acc[4 + ii][jj], 0, 0, 0);
    PRIO0();
    // Boundary: require tile s+1 landed. Steady state: newest 8 outstanding
    // loads = tiles s+2,s+3 -> vmcnt(8). Tail: s==NT-3 -> newest 4 = tile
    // NT-1 -> vmcnt(4); s==NT-2 -> vmcnt(0); s==NT-1 -> none.
    if (s < NT_ - 3) { VMCNT(8); }
    else if (s == NT_ - 3) { VMCNT(4); }
    else if (s == NT_ - 2) { VMCNT(0); }
    BAR();
  }

  // Epilogue: C/D layout col = lane&15, row = (lane>>4)*4 + reg  [m89]
#pragma unroll
  for (int i = 0; i < 8; ++i)
#pragma unroll
    for (int j = 0; j < 4; ++j)
#pragma unroll
      for (int r = 0; r < 4; ++r) {
        const int grow = m0 + wm * 128 + i * 16 + cl * 4 + r;
        const int gcol = n0 + wn * 64 + j * 16 + rl;
        C[(size_t)grow * N_ + gcol] = acc[i][j][r];
      }
}

// ---------------------------------------------------------------- fallback GEMM (fp32 in, 128^2)
__global__ __launch_bounds__(256) void gemm_fb(const float* __restrict__ Ap,
                                               const float* __restrict__ Bp,
                                               float* __restrict__ Cp) {
  __shared__ __align__(1024) unsigned char smem[2][16384];
  const int tid = threadIdx.x;
  const int bid = blockIdx.x;
  const int swz = (bid & 7) * 1000 + (bid >> 3);
  const int nblk = swz >> 5;
  const int mblk = swz & 31;
  const int m0 = mblk * 128;
  const int n0 = nblk * 128;
  const int w = tid >> 6, lane = tid & 63;
  const int wm = w >> 1, wn = w & 1;
  const int rl = lane & 15, cl = lane >> 4;

  f32x4 acc[4][4];
#pragma unroll
  for (int i = 0; i < 4; ++i)
#pragma unroll
    for (int j = 0; j < 4; ++j) acc[i][j] = (f32x4){0.f, 0.f, 0.f, 0.f};

  auto stage = [&](int buf, int kt) {
    const int k0 = kt * 32;
#pragma unroll
    for (int j = 0; j < 2; ++j) {
      const int t = j * 256 + tid;
      const int row = t >> 2;
      const int c = t & 3;
      const int rp = row >> 1;
      const int pp = ((row & 1) * 4 + c) ^ (rp & 7);
      const int lb = rp * 128 + pp * 16;
      {
        const float4* g = (const float4*)(Ap + (size_t)(m0 + row) * K_ + k0 + c * 8);
        float4 x = g[0], y = g[1];
        bf16x8 v;
        v[0] = (__bf16)x.x; v[1] = (__bf16)x.y; v[2] = (__bf16)x.z; v[3] = (__bf16)x.w;
        v[4] = (__bf16)y.x; v[5] = (__bf16)y.y; v[6] = (__bf16)y.z; v[7] = (__bf16)y.w;
        *(bf16x8*)(&smem[buf][lb]) = v;
      }
      {
        const float4* g = (const float4*)(Bp + (size_t)(n0 + row) * K_ + k0 + c * 8);
        float4 x = g[0], y = g[1];
        bf16x8 v;
        v[0] = (__bf16)x.x; v[1] = (__bf16)x.y; v[2] = (__bf16)x.z; v[3] = (__bf16)x.w;
        v[4] = (__bf16)y.x; v[5] = (__bf16)y.y; v[6] = (__bf16)y.z; v[7] = (__bf16)y.w;
        *(bf16x8*)(&smem[buf][8192 + lb]) = v;
      }
    }
  };
  auto ldfrag = [&](const unsigned char* base, int row, int c) -> bf16x8 {
    const int rp = row >> 1;
    const int pp = ((row & 1) * 4 + c) ^ (rp & 7);
    return *(const bf16x8*)(base + rp * 128 + pp * 16);
  };
  auto compute = [&](int buf) {
    const unsigned char* bA = smem[buf];
    const unsigned char* bB = smem[buf] + 8192;
    bf16x8 af[4], bfv[4];
#pragma unroll
    for (int i = 0; i < 4; ++i) af[i] = ldfrag(bA, wm * 64 + i * 16 + rl, cl);
#pragma unroll
    for (int j = 0; j < 4; ++j) bfv[j] = ldfrag(bB, wn * 64 + j * 16 + rl, cl);
#pragma unroll
    for (int i = 0; i < 4; ++i)
#pragma unroll
      for (int j = 0; j < 4; ++j)
        acc[i][j] = __builtin_amdgcn_mfma_f32_16x16x32_bf16(af[i], bfv[j],
                                                            acc[i][j], 0, 0, 0);
  };

  stage(0, 0);
  __syncthreads();
  for (int kt = 0; kt < 128; kt += 2) {
    if (kt + 1 < 128) stage(1, kt + 1);
    compute(0);
    __syncthreads();
    if (kt + 2 < 128) stage(0, kt + 2);
    compute(1);
    __syncthreads();
  }
#pragma unroll
  for (int i = 0; i < 4; ++i)
#pragma unroll
    for (int j = 0; j < 4; ++j)
#pragma unroll
      for (int r = 0; r < 4; ++r) {
        const int grow = m0 + wm * 64 + i * 16 + cl * 4 + r;
        const int gcol = n0 + wn * 64 + j * 16 + rl;
        Cp[(size_t)grow * N_ + gcol] = acc[i][j][r];
      }
}

// ---------------------------------------------------------------- CE loss (online, 1-pass)
__global__ __launch_bounds__(256) void ce_rows(const float* __restrict__ logits,
                                               const int* __restrict__ labels,
                                               float* __restrict__ nll) {
  const int r = blockIdx.x;
  const int b = r / SM1;
  const int t = r - b * SM1;
  const float* row = logits + (size_t)(b * S_ + t) * N_;
  float m = -3.4e38f, s = 0.f;
  const float4* row4 = (const float4*)row;
  for (int i = threadIdx.x; i < 7936; i += 256) {  // 7936*4 = 31744
    float4 v = row4[i];
    float mx = fmaxf(fmaxf(v.x, v.y), fmaxf(v.z, v.w));
    if (mx > m) { s *= __expf(m - mx); m = mx; }
    s += __expf(v.x - m) + __expf(v.y - m) + __expf(v.z - m) + __expf(v.w - m);
  }
  {  // remainder: 256 elements
    float v = row[31744 + threadIdx.x];
    if (v > m) { s *= __expf(m - v); m = v; }
    s += __expf(v - m);
  }
#pragma unroll
  for (int o = 32; o > 0; o >>= 1) {
    float m2 = __shfl_xor(m, o), s2 = __shfl_xor(s, o);
    float mn = fmaxf(m, m2);
    s = s * __expf(m - mn) + s2 * __expf(m2 - mn);
    m = mn;
  }
  __shared__ float rm[4], rs[4];
  if ((threadIdx.x & 63) == 0) { rm[threadIdx.x >> 6] = m; rs[threadIdx.x >> 6] = s; }
  __syncthreads();
  if (threadIdx.x == 0) {
    float M = fmaxf(fmaxf(rm[0], rm[1]), fmaxf(rm[2], rm[3]));
    float S = rs[0] * __expf(rm[0] - M) + rs[1] * __expf(rm[1] - M) +
              rs[2] * __expf(rm[2] - M) + rs[3] * __expf(rm[3] - M);
    nll[r] = M + __logf(S) - row[labels[b * S_ + t + 1]];
  }
}

__global__ __launch_bounds__(256) void reduce_loss(const float* __restrict__ nll,
                                                   float* __restrict__ out) {
  float s = 0.f;
  for (int i = threadIdx.x; i < NROWS; i += 256) s += nll[i];
#pragma unroll
  for (int o = 32; o > 0; o >>= 1) s += __shfl_xor(s, o);
  __shared__ float sb[4];
  if ((threadIdx.x & 63) == 0) sb[threadIdx.x >> 6] = s;
  __syncthreads();
  if (threadIdx.x == 0) out[0] = (sb[0] + sb[1] + sb[2] + sb[3]) / (float)NROWS;
}

// ---------------------------------------------------------------- launch
extern "C" void kernel_launch(void* const* d_in, const int* in_sizes, int n_in,
                              void* d_out, int out_size, void* d_ws,
                              size_t ws_size, hipStream_t stream) {
  const float* h = (const float*)d_in[0];
  const float* Wf = (const float*)d_in[1];
  const int* labels = (const int*)d_in[2];
  float* out = (float*)d_out;
  float* logits = out + 1;

  const size_t abytes = (size_t)M_ * K_ * 2;
  const size_t bbytes = (size_t)N_ * K_ * 2;
  const size_t need = abytes + bbytes + (size_t)NROWS * sizeof(float);

  if (ws_size >= need) {
    unsigned char* base = (unsigned char*)d_ws;
    __bf16* hA = (__bf16*)base;
    __bf16* wB = (__bf16*)(base + abytes);
    float* nll = (float*)(base + abytes + bbytes);
    cvt_f32_to_bf16<<<2048, 256, 0, stream>>>(h, (bf16x8*)hA,
                                              (long)((size_t)M_ * K_ / 8));
    cvt_f32_to_bf16<<<4096, 256, 0, stream>>>(Wf, (bf16x8*)wB,
                                              (long)((size_t)N_ * K_ / 8));
    gemm256<<<2000, 512, 0, stream>>>(hA, wB, logits);
    ce_rows<<<4094, 256, 0, stream>>>(logits, labels, nll);
    reduce_loss<<<1, 256, 0, stream>>>(nll, out);
  } else {
    float* nll = (float*)d_ws;
    gemm_fb<<<8000, 256, 0, stream>>>(h, Wf, logits);
    ce_rows<<<4094, 256, 0, stream>>>(logits, labels, nll);
    reduce_loss<<<1, 256, 0, stream>>>(nll, out);
  }
}

// Round 5
// 1243.561 us; speedup vs baseline: 1.6004x; 1.0866x over previous
//
#include <hip/hip_runtime.h>
#include <hip/hip_bf16.h>

#define M_ 4096
#define N_ 32000
#define K_ 4096
#define S_ 2048
#define SM1 2047
#define NROWS 4094
#define NT_ 64  // K-tiles of BK=64

typedef __bf16 bf16x8 __attribute__((ext_vector_type(8)));
typedef float f32x4 __attribute__((ext_vector_type(4)));

#define GLDS16(g, l)                                                         \
  __builtin_amdgcn_global_load_lds(                                          \
      (__attribute__((address_space(1))) const void*)(g),                    \
      (__attribute__((address_space(3))) void*)(l), 16, 0, 0)
#define BAR() __builtin_amdgcn_s_barrier()
#define PRIO1() __builtin_amdgcn_s_setprio(1)
#define PRIO0() __builtin_amdgcn_s_setprio(0)
#define VMCNT(n) asm volatile("s_waitcnt vmcnt(" #n ")" ::: "memory")

// ---------------------------------------------------------------- cvt kernel
__global__ __launch_bounds__(256) void cvt_f32_to_bf16(
    const float* __restrict__ in, bf16x8* __restrict__ out, long n8) {
  long i0 = (long)blockIdx.x * blockDim.x + threadIdx.x;
  long stride = (long)gridDim.x * blockDim.x;
  for (long i = i0; i < n8; i += stride) {
    const float4* p = reinterpret_cast<const float4*>(in) + i * 2;
    float4 a = p[0];
    float4 b = p[1];
    bf16x8 v;
    v[0] = (__bf16)a.x; v[1] = (__bf16)a.y; v[2] = (__bf16)a.z; v[3] = (__bf16)a.w;
    v[4] = (__bf16)b.x; v[5] = (__bf16)b.y; v[6] = (__bf16)b.z; v[7] = (__bf16)b.w;
    out[i] = v;
  }
}

// ---------------------------------------------------------------- GEMM 256x256, BK=64, overlap schedule v2
// C[m,n] = sum_k A[m,k]*B[n,k]. 512 thr = 8 waves (2m x 4n), per-wave 128x64
// = acc[8][4]. LDS 2 x 64KB (A 32K | B 32K), 128-B rows, slot = c ^ (row&7)
// (R2's measured-conflict-free pair: linear GLDS dest + inverse-swz source).
//
// Halfsets (2 GLDS/thread each):
//   SA0 = A rows bit6==0 (a_lo)   SA1 = A rows bit6==1 (a_hi)
//   SB0 = B rows bit5==0 (b0)     SB1 = B rows bit5==1 (b1)
// Tile s phases (4 barriers/tile), staging tile s+1:
//   ph1: stage SA0; MFMA al*b0;            VMCNT(2); BAR   <- SA1(s),SB1(s) collective
//   ph2: stage SB0; read b1r then ah; MFMA al*b1; BAR      (ah hidden under MFMA)
//   ph3: stage SA1; MFMA ah*b0; BAR
//   ph4: stage SB1; MFMA ah*b1; VMCNT(4); BAR; read al,b0r(s+1)  <- SA0,SB0(s+1) collective
// vmcnt audit (in-order): boundary leaves {SA1,SB1}(s+1)=4; ph1 leaves
// SA0(s+1)=2. Tail: last tile ph1 -> VMCNT(0); no boundary wait/reads.
// Every cross-wave read sits after a barrier preceded by the covering VMCNT
// in ALL waves (the R4 bug was reading right after a local-only vmcnt).
// WAR: each halfset overwrite is >=3 barriers after its last reader's
// consuming MFMA (reads complete before their MFMA, which precedes a BAR).
__global__ __launch_bounds__(512, 2) void gemm256(
    const __bf16* __restrict__ A, const __bf16* __restrict__ B,
    float* __restrict__ C) {
  __shared__ __align__(1024) unsigned char smem[2][65536];

  const int tid = threadIdx.x;
  const int bid = blockIdx.x;
  // Bijective XCD swizzle (2000 % 8 == 0), n-panel-major within XCD.
  const int wg = (bid & 7) * 250 + (bid >> 3);
  const int nblk = wg >> 4;  // 0..124
  const int mblk = wg & 15;  // 0..15
  const int m0 = mblk * 256;
  const int n0 = nblk * 256;

  const int w = tid >> 6;
  const int lane = tid & 63;
  const int wm = w >> 2;  // 0..1
  const int wn = w & 3;   // 0..3
  const int rl = lane & 15;
  const int cl = lane >> 4;
  const int srow = tid >> 3;  // staging row-within-64 block
  const int scc = tid & 7;    // staging dest chunk

  f32x4 acc[8][4];
#pragma unroll
  for (int i = 0; i < 8; ++i)
#pragma unroll
    for (int j = 0; j < 4; ++j) acc[i][j] = (f32x4){0.f, 0.f, 0.f, 0.f};

  // A halfset q: 64-row blocks at q*64 and 128+q*64.
  auto stA2 = [&](int nbuf, int kt, int q) {
#pragma unroll
    for (int j = 0; j < 2; ++j) {
      const int r0 = q * 64 + j * 128;
      const int row = r0 + srow;
      const int c = scc ^ (row & 7);
      GLDS16(A + (size_t)(m0 + row) * K_ + kt * 64 + c * 8,
             &smem[nbuf][r0 * 128 + tid * 16]);
    }
  };
  // B halfset q: 32-row stripes at {0,64,128,192}+q*32.
  auto stB2 = [&](int nbuf, int kt, int q) {
#pragma unroll
    for (int j = 0; j < 2; ++j) {
      const int cg = j * 512 + tid;
      const int rl_ = cg >> 3;
      const int row = ((rl_ >> 5) << 6) + q * 32 + (rl_ & 31);
      const int cc = cg & 7;
      const int c = cc ^ (row & 7);
      GLDS16(B + (size_t)(n0 + row) * K_ + kt * 64 + c * 8,
             &smem[nbuf][32768 + row * 128 + cc * 16]);
    }
  };
  auto ld = [&](const unsigned char* base, int row, int c) -> bf16x8 {
    return *(const bf16x8*)(base + row * 128 + (((c ^ row) & 7) << 4));
  };

  // Prologue: tile 0 halfsets in consumption order; collective wait SA0,SB0.
  stA2(0, 0, 0); stB2(0, 0, 0); stA2(0, 0, 1); stB2(0, 0, 1);
  VMCNT(4);
  BAR();

  bf16x8 al[4][2], ah[4][2], b0r[2][2], b1r[2][2];
#pragma unroll
  for (int jj = 0; jj < 2; ++jj)
#pragma unroll
    for (int ks = 0; ks < 2; ++ks)
      b0r[jj][ks] = ld(smem[0] + 32768, wn * 64 + jj * 16 + rl, ks * 4 + cl);
#pragma unroll
  for (int ii = 0; ii < 4; ++ii)
#pragma unroll
    for (int ks = 0; ks < 2; ++ks)
      al[ii][ks] = ld(smem[0], wm * 128 + ii * 16 + rl, ks * 4 + cl);

  for (int s = 0; s < NT_; ++s) {
    const int cur = s & 1;
    const int nxt = cur ^ 1;
    const unsigned char* bA = smem[cur];
    const unsigned char* bB = smem[cur] + 32768;
    const bool st = (s + 1 < NT_);

    // ---- ph1: stage SA0(s+1); MFMA a_lo x b0; collective wait SA1,SB1(s)
    if (st) stA2(nxt, s + 1, 0);
    PRIO1();
#pragma unroll
    for (int ii = 0; ii < 4; ++ii)
#pragma unroll
      for (int jj = 0; jj < 2; ++jj)
#pragma unroll
        for (int ks = 0; ks < 2; ++ks)
          acc[ii][jj] = __builtin_amdgcn_mfma_f32_16x16x32_bf16(
              al[ii][ks], b0r[jj][ks], acc[ii][jj], 0, 0, 0);
    PRIO0();
    if (st) { VMCNT(2); } else { VMCNT(0); }
    BAR();

    // ---- ph2: stage SB0(s+1); read b1 (first) + a_hi; MFMA a_lo x b1
    if (st) stB2(nxt, s + 1, 0);
#pragma unroll
    for (int jj = 0; jj < 2; ++jj)
#pragma unroll
      for (int ks = 0; ks < 2; ++ks)
        b1r[jj][ks] = ld(bB, wn * 64 + 32 + jj * 16 + rl, ks * 4 + cl);
#pragma unroll
    for (int ii = 0; ii < 4; ++ii)
#pragma unroll
      for (int ks = 0; ks < 2; ++ks)
        ah[ii][ks] = ld(bA, wm * 128 + 64 + ii * 16 + rl, ks * 4 + cl);
    PRIO1();
#pragma unroll
    for (int ii = 0; ii < 4; ++ii)
#pragma unroll
      for (int jj = 0; jj < 2; ++jj)
#pragma unroll
        for (int ks = 0; ks < 2; ++ks)
          acc[ii][2 + jj] = __builtin_amdgcn_mfma_f32_16x16x32_bf16(
              al[ii][ks], b1r[jj][ks], acc[ii][2 + jj], 0, 0, 0);
    PRIO0();
    BAR();

    // ---- ph3: stage SA1(s+1); MFMA a_hi x b0
    if (st) stA2(nxt, s + 1, 1);
    PRIO1();
#pragma unroll
    for (int ii = 0; ii < 4; ++ii)
#pragma unroll
      for (int jj = 0; jj < 2; ++jj)
#pragma unroll
        for (int ks = 0; ks < 2; ++ks)
          acc[4 + ii][jj] = __builtin_amdgcn_mfma_f32_16x16x32_bf16(
              ah[ii][ks], b0r[jj][ks], acc[4 + ii][jj], 0, 0, 0);
    PRIO0();
    BAR();

    // ---- ph4: stage SB1(s+1); MFMA a_hi x b1; boundary wait; next reads
    if (st) stB2(nxt, s + 1, 1);
    PRIO1();
#pragma unroll
    for (int ii = 0; ii < 4; ++ii)
#pragma unroll
      for (int jj = 0; jj < 2; ++jj)
#pragma unroll
        for (int ks = 0; ks < 2; ++ks)
          acc[4 + ii][2 + jj] = __builtin_amdgcn_mfma_f32_16x16x32_bf16(
              ah[ii][ks], b1r[jj][ks], acc[4 + ii][2 + jj], 0, 0, 0);
    PRIO0();
    if (st) VMCNT(4);  // SA0,SB0(s+1) landed; SA1,SB1(s+1) stay in flight
    BAR();
    if (st) {
      const unsigned char* nA = smem[nxt];
      const unsigned char* nB = smem[nxt] + 32768;
#pragma unroll
      for (int jj = 0; jj < 2; ++jj)
#pragma unroll
        for (int ks = 0; ks < 2; ++ks)
          b0r[jj][ks] = ld(nB, wn * 64 + jj * 16 + rl, ks * 4 + cl);
#pragma unroll
      for (int ii = 0; ii < 4; ++ii)
#pragma unroll
        for (int ks = 0; ks < 2; ++ks)
          al[ii][ks] = ld(nA, wm * 128 + ii * 16 + rl, ks * 4 + cl);
    }
  }

  // Epilogue: C/D layout col = lane&15, row = (lane>>4)*4 + reg  [m89]
#pragma unroll
  for (int i = 0; i < 8; ++i)
#pragma unroll
    for (int j = 0; j < 4; ++j)
#pragma unroll
      for (int r = 0; r < 4; ++r) {
        const int grow = m0 + wm * 128 + i * 16 + cl * 4 + r;
        const int gcol = n0 + wn * 64 + j * 16 + rl;
        C[(size_t)grow * N_ + gcol] = acc[i][j][r];
      }
}

// ---------------------------------------------------------------- fallback GEMM (fp32 in, 128^2)
__global__ __launch_bounds__(256) void gemm_fb(const float* __restrict__ Ap,
                                               const float* __restrict__ Bp,
                                               float* __restrict__ Cp) {
  __shared__ __align__(1024) unsigned char smem[2][16384];
  const int tid = threadIdx.x;
  const int bid = blockIdx.x;
  const int swz = (bid & 7) * 1000 + (bid >> 3);
  const int nblk = swz >> 5;
  const int mblk = swz & 31;
  const int m0 = mblk * 128;
  const int n0 = nblk * 128;
  const int w = tid >> 6, lane = tid & 63;
  const int wm = w >> 1, wn = w & 1;
  const int rl = lane & 15, cl = lane >> 4;

  f32x4 acc[4][4];
#pragma unroll
  for (int i = 0; i < 4; ++i)
#pragma unroll
    for (int j = 0; j < 4; ++j) acc[i][j] = (f32x4){0.f, 0.f, 0.f, 0.f};

  auto stage = [&](int buf, int kt) {
    const int k0 = kt * 32;
#pragma unroll
    for (int j = 0; j < 2; ++j) {
      const int t = j * 256 + tid;
      const int row = t >> 2;
      const int c = t & 3;
      const int rp = row >> 1;
      const int pp = ((row & 1) * 4 + c) ^ (rp & 7);
      const int lb = rp * 128 + pp * 16;
      {
        const float4* g = (const float4*)(Ap + (size_t)(m0 + row) * K_ + k0 + c * 8);
        float4 x = g[0], y = g[1];
        bf16x8 v;
        v[0] = (__bf16)x.x; v[1] = (__bf16)x.y; v[2] = (__bf16)x.z; v[3] = (__bf16)x.w;
        v[4] = (__bf16)y.x; v[5] = (__bf16)y.y; v[6] = (__bf16)y.z; v[7] = (__bf16)y.w;
        *(bf16x8*)(&smem[buf][lb]) = v;
      }
      {
        const float4* g = (const float4*)(Bp + (size_t)(n0 + row) * K_ + k0 + c * 8);
        float4 x = g[0], y = g[1];
        bf16x8 v;
        v[0] = (__bf16)x.x; v[1] = (__bf16)x.y; v[2] = (__bf16)x.z; v[3] = (__bf16)x.w;
        v[4] = (__bf16)y.x; v[5] = (__bf16)y.y; v[6] = (__bf16)y.z; v[7] = (__bf16)y.w;
        *(bf16x8*)(&smem[buf][8192 + lb]) = v;
      }
    }
  };
  auto ldfrag = [&](const unsigned char* base, int row, int c) -> bf16x8 {
    const int rp = row >> 1;
    const int pp = ((row & 1) * 4 + c) ^ (rp & 7);
    return *(const bf16x8*)(base + rp * 128 + pp * 16);
  };
  auto compute = [&](int buf) {
    const unsigned char* bA = smem[buf];
    const unsigned char* bB = smem[buf] + 8192;
    bf16x8 af[4], bfv[4];
#pragma unroll
    for (int i = 0; i < 4; ++i) af[i] = ldfrag(bA, wm * 64 + i * 16 + rl, cl);
#pragma unroll
    for (int j = 0; j < 4; ++j) bfv[j] = ldfrag(bB, wn * 64 + j * 16 + rl, cl);
#pragma unroll
    for (int i = 0; i < 4; ++i)
#pragma unroll
      for (int j = 0; j < 4; ++j)
        acc[i][j] = __builtin_amdgcn_mfma_f32_16x16x32_bf16(af[i], bfv[j],
                                                            acc[i][j], 0, 0, 0);
  };

  stage(0, 0);
  __syncthreads();
  for (int kt = 0; kt < 128; kt += 2) {
    if (kt + 1 < 128) stage(1, kt + 1);
    compute(0);
    __syncthreads();
    if (kt + 2 < 128) stage(0, kt + 2);
    compute(1);
    __syncthreads();
  }
#pragma unroll
  for (int i = 0; i < 4; ++i)
#pragma unroll
    for (int j = 0; j < 4; ++j)
#pragma unroll
      for (int r = 0; r < 4; ++r) {
        const int grow = m0 + wm * 64 + i * 16 + cl * 4 + r;
        const int gcol = n0 + wn * 64 + j * 16 + rl;
        Cp[(size_t)grow * N_ + gcol] = acc[i][j][r];
      }
}

// ---------------------------------------------------------------- CE loss (online, 1-pass)
__global__ __launch_bounds__(256) void ce_rows(const float* __restrict__ logits,
                                               const int* __restrict__ labels,
                                               float* __restrict__ nll) {
  const int r = blockIdx.x;
  const int b = r / SM1;
  const int t = r - b * SM1;
  const float* row = logits + (size_t)(b * S_ + t) * N_;
  float m = -3.4e38f, s = 0.f;
  const float4* row4 = (const float4*)row;
  for (int i = threadIdx.x; i < 7936; i += 256) {  // 7936*4 = 31744
    float4 v = row4[i];
    float mx = fmaxf(fmaxf(v.x, v.y), fmaxf(v.z, v.w));
    if (mx > m) { s *= __expf(m - mx); m = mx; }
    s += __expf(v.x - m) + __expf(v.y - m) + __expf(v.z - m) + __expf(v.w - m);
  }
  {  // remainder: 256 elements
    float v = row[31744 + threadIdx.x];
    if (v > m) { s *= __expf(m - v); m = v; }
    s += __expf(v - m);
  }
#pragma unroll
  for (int o = 32; o > 0; o >>= 1) {
    float m2 = __shfl_xor(m, o), s2 = __shfl_xor(s, o);
    float mn = fmaxf(m, m2);
    s = s * __expf(m - mn) + s2 * __expf(m2 - mn);
    m = mn;
  }
  __shared__ float rm[4], rs[4];
  if ((threadIdx.x & 63) == 0) { rm[threadIdx.x >> 6] = m; rs[threadIdx.x >> 6] = s; }
  __syncthreads();
  if (threadIdx.x == 0) {
    float M = fmaxf(fmaxf(rm[0], rm[1]), fmaxf(rm[2], rm[3]));
    float S = rs[0] * __expf(rm[0] - M) + rs[1] * __expf(rm[1] - M) +
              rs[2] * __expf(rm[2] - M) + rs[3] * __expf(rm[3] - M);
    nll[r] = M + __logf(S) - row[labels[b * S_ + t + 1]];
  }
}

__global__ __launch_bounds__(256) void reduce_loss(const float* __restrict__ nll,
                                                   float* __restrict__ out) {
  float s = 0.f;
  for (int i = threadIdx.x; i < NROWS; i += 256) s += nll[i];
#pragma unroll
  for (int o = 32; o > 0; o >>= 1) s += __shfl_xor(s, o);
  __shared__ float sb[4];
  if ((threadIdx.x & 63) == 0) sb[threadIdx.x >> 6] = s;
  __syncthreads();
  if (threadIdx.x == 0) out[0] = (sb[0] + sb[1] + sb[2] + sb[3]) / (float)NROWS;
}

// ---------------------------------------------------------------- launch
extern "C" void kernel_launch(void* const* d_in, const int* in_sizes, int n_in,
                              void* d_out, int out_size, void* d_ws,
                              size_t ws_size, hipStream_t stream) {
  const float* h = (const float*)d_in[0];
  const float* Wf = (const float*)d_in[1];
  const int* labels = (const int*)d_in[2];
  float* out = (float*)d_out;
  float* logits = out + 1;

  const size_t abytes = (size_t)M_ * K_ * 2;
  const size_t bbytes = (size_t)N_ * K_ * 2;
  const size_t need = abytes + bbytes + (size_t)NROWS * sizeof(float);

  if (ws_size >= need) {
    unsigned char* base = (unsigned char*)d_ws;
    __bf16* hA = (__bf16*)base;
    __bf16* wB = (__bf16*)(base + abytes);
    float* nll = (float*)(base + abytes + bbytes);
    cvt_f32_to_bf16<<<2048, 256, 0, stream>>>(h, (bf16x8*)hA,
                                              (long)((size_t)M_ * K_ / 8));
    cvt_f32_to_bf16<<<4096, 256, 0, stream>>>(Wf, (bf16x8*)wB,
                                              (long)((size_t)N_ * K_ / 8));
    gemm256<<<2000, 512, 0, stream>>>(hA, wB, logits);
    ce_rows<<<4094, 256, 0, stream>>>(logits, labels, nll);
    reduce_loss<<<1, 256, 0, stream>>>(nll, out);
  } else {
    float* nll = (float*)d_ws;
    gemm_fb<<<8000, 256, 0, stream>>>(h, Wf, logits);
    ce_rows<<<4094, 256, 0, stream>>>(logits, labels, nll);
    reduce_loss<<<1, 256, 0, stream>>>(nll, out);
  }
}